// Round 11
// baseline (300.232 us; speedup 1.0000x reference)
//
#include <hip/hip_runtime.h>

#define T_TOK 16384
#define DM 1024
#define DFF 4096
#define NE 8
#define CAP 320
#define RP 384     // per-expert padded rows (3 x 128 tiles)
#define RSPLIT 8
#define KSP (DM / RSPLIT)   // 128

typedef __attribute__((ext_vector_type(8))) short bf16x8;
typedef __attribute__((ext_vector_type(4))) float f32x4;
typedef __attribute__((ext_vector_type(4))) unsigned int u32x4;

__device__ __forceinline__ unsigned short f2bf(float f) {
    unsigned int u = __builtin_bit_cast(unsigned int, f);
    u += 0x7FFFu + ((u >> 16) & 1u);   // RNE (finite inputs)
    return (unsigned short)(u >> 16);
}

__device__ __forceinline__ void gload_lds16(const void* g, void* l) {
    __builtin_amdgcn_global_load_lds(
        (const __attribute__((address_space(1))) unsigned int*)g,
        (__attribute__((address_space(3))) unsigned int*)l,
        16, 0, 0);
}

// ---------------- router pass 1 (+ init sumprob/lb in block (0,0)) ----------------
__global__ __launch_bounds__(256) void k_logits(
    const float* __restrict__ x, const float* __restrict__ rw,
    float* __restrict__ part, float* __restrict__ sumprob,
    float* __restrict__ out_lb)
{
    if (blockIdx.x == 0 && blockIdx.y == 0) {
        if (threadIdx.x < NE) sumprob[threadIdx.x] = 0.f;
        if (threadIdx.x == NE) *out_lb = 0.f;
    }
    __shared__ float ws_[KSP][NE];
    __shared__ float xs[256][17];
    const int s = blockIdx.y, t0 = blockIdx.x * 256, tid = threadIdx.x;

    ((float4*)&ws_[0][0])[tid] = ((const float4*)(rw + s * KSP * NE))[tid];

    float a[NE] = {};
    for (int c = 0; c < KSP / 16; ++c) {
        __syncthreads();
        #pragma unroll
        for (int j = 0; j < 4; ++j) {
            int idx = tid + j * 256;
            int row = idx >> 2, f = idx & 3;
            float4 v = *(const float4*)(x + (size_t)(t0 + row) * DM + s * KSP + c * 16 + f * 4);
            xs[row][f * 4 + 0] = v.x; xs[row][f * 4 + 1] = v.y;
            xs[row][f * 4 + 2] = v.z; xs[row][f * 4 + 3] = v.w;
        }
        __syncthreads();
        #pragma unroll
        for (int k = 0; k < 16; ++k) {
            float xv = xs[tid][k];
            const float* wr = &ws_[c * 16 + k][0];
            #pragma unroll
            for (int e = 0; e < NE; ++e) a[e] += xv * wr[e];
        }
    }
    float4* dst = (float4*)(part + ((size_t)s * T_TOK + t0 + tid) * NE);
    dst[0] = make_float4(a[0], a[1], a[2], a[3]);
    dst[1] = make_float4(a[4], a[5], a[6], a[7]);
}

// ---------------- router pass 2 ----------------
__global__ __launch_bounds__(256) void k_reduce(
    const float* __restrict__ part, const float* __restrict__ rb,
    int* __restrict__ eidx, float* __restrict__ sumprob)
{
    int t = blockIdx.x * 256 + threadIdx.x;
    float a[NE];
    #pragma unroll
    for (int e = 0; e < NE; ++e) a[e] = rb[e];
    for (int s = 0; s < RSPLIT; ++s) {        // fixed order -> deterministic
        const float4* p = (const float4*)(part + ((size_t)s * T_TOK + t) * NE);
        float4 v0 = p[0], v1 = p[1];
        a[0] += v0.x; a[1] += v0.y; a[2] += v0.z; a[3] += v0.w;
        a[4] += v1.x; a[5] += v1.y; a[6] += v1.z; a[7] += v1.w;
    }
    float m = a[0]; int bi = 0;
    #pragma unroll
    for (int e = 1; e < NE; ++e) if (a[e] > m) { m = a[e]; bi = e; }
    float p[NE], s = 0.f;
    #pragma unroll
    for (int e = 0; e < NE; ++e) { p[e] = __expf(a[e] - m); s += p[e]; }
    float inv = 1.f / s;
    eidx[t] = bi;
    #pragma unroll
    for (int e = 0; e < NE; ++e) {
        float v = p[e] * inv;
        #pragma unroll
        for (int o = 32; o > 0; o >>= 1) v += __shfl_down(v, o);
        if ((threadIdx.x & 63) == 0) atomicAdd(&sumprob[e], v);
    }
}

// ---------------- per-expert rank scan (+ fused lb-loss term) ----------------
__global__ __launch_bounds__(1024) void k_scan(
    const int* __restrict__ eidx, int* __restrict__ s2t,
    int* __restrict__ token_slot, const float* __restrict__ sumprob,
    float* __restrict__ out_lb)
{
    const int e = blockIdx.x;
    const int tid = threadIdx.x, lane = tid & 63, w = tid >> 6;
    __shared__ int wts[16];

    for (int i = tid; i < CAP; i += 1024) s2t[e * CAP + i] = -1;
    __syncthreads();

    int running = 0;
    for (int base = 0; base < T_TOK; base += 1024) {
        int t = base + tid;
        bool flag = (eidx[t] == e);
        unsigned long long mask = __ballot(flag);
        int wp = __popcll(mask & ((1ull << lane) - 1ull));
        if (lane == 0) wts[w] = __popcll(mask);
        __syncthreads();
        int woff = 0, btot = 0;
        #pragma unroll
        for (int j = 0; j < 16; ++j) { int v = wts[j]; btot += v; if (j < w) woff += v; }
        if (flag) {
            int rank = running + woff + wp;
            if (rank < CAP) {
                s2t[e * CAP + rank] = t;
                token_slot[t] = e * RP + rank;
            } else {
                token_slot[t] = -1;
            }
        }
        running += btot;
        __syncthreads();
    }
    if (tid == 0)
        atomicAdd(out_lb, (float)NE * (float)running * sumprob[e] /
                          ((float)T_TOK * (float)T_TOK));
}

// ---------------- gather kept tokens -> bf16 (+ zero y row) ----------------
__global__ __launch_bounds__(256) void k_gather(
    const float* __restrict__ x, const int* __restrict__ s2t,
    unsigned short* __restrict__ xb, float4* __restrict__ y)
{
    int r = blockIdx.x;
    int e = r / RP, i = r - e * RP;
    int tok = (i < CAP) ? s2t[e * CAP + i] : -1;
    int tid = threadIdx.x;

    y[(size_t)r * (DM / 4) + tid] = make_float4(0.f, 0.f, 0.f, 0.f);

    unsigned short* dst = xb + (size_t)r * DM + tid * 4;
    if (tok >= 0) {
        float4 v = reinterpret_cast<const float4*>(x + (size_t)tok * DM)[tid];
        short4 b = make_short4((short)f2bf(v.x), (short)f2bf(v.y),
                               (short)f2bf(v.z), (short)f2bf(v.w));
        *reinterpret_cast<short4*>(dst) = b;
    } else {
        *reinterpret_cast<short4*>(dst) = make_short4(0, 0, 0, 0);
    }
}

// ---------------- grouped GEMM, inline f32->bf16 B-staging -----------------------
// A: bf16 [NE][RP][K] k-contig, DMA-staged (global_load_lds) into lA[2][128][4].
// B: native f32 weights [NE][K][N]; per K-step reg-staged with slot mapping
//    q=tid&3, col=tid>>2 so the ds_write_b128 address = tid*16 (write
//    conflict-free) into the proven [col][kg] read layout. cvt via
//    v_cvt_pk_bf16_f32 (RNE). Eliminates the separate transpose/cvt pass:
//    weight traffic = one f32 read (floor).
// Sync: round-7 scheme (2-buf, vmcnt(0)+lgkmcnt(0)+barrier per K-step); TLP
//    (3 blocks/CU) hides the drain; XCD-chunk e=j&7 keeps each expert's
//    weights in one L2.
// MFMA 16x16x32 bf16: A-frag row=lane&15, k=8*(lane>>4)+j; C/D col=lane&15,
//    row=4*(lane>>4)+i.
template<int NK, int RS, int N, int NTL, bool RELU, bool YOUT, typename OutT>
__global__ __launch_bounds__(256, 3) void k_gemm(
    const unsigned short* __restrict__ A, const float* __restrict__ Bw,
    const float* __restrict__ bias, OutT* __restrict__ C)
{
    __shared__ bf16x8 lA[2][128][4];   // 16 KB
    __shared__ bf16x8 lB[2][128][4];   // 16 KB

    const int j = blockIdx.x;
    const int e = j & 7;               // XCD-chunk = expert
    const int s = j >> 3;
    const int split = s / (NTL * 3);
    const int r2 = s % (NTL * 3);
    const int nt = r2 / 3, mt = r2 % 3;

    const int m0 = mt * 128;
    const int n0 = nt * 128;
    const int kb0 = split * (NK * 32);
    const int tid = threadIdx.x, lane = tid & 63;
    const int w = tid >> 6, wm = w >> 1, wn = w & 1;
    const int lrow = lane & 15, kg = lane >> 4;

    const unsigned short* Ae = A + ((size_t)e * RP + m0) * RS + kb0;
    const float* Be = Bw + (size_t)e * RS * N + (size_t)kb0 * N + n0;

    auto stage_A = [&](int buf, int ks) {
        bf16x8* ld = &lA[buf][0][0];
        #pragma unroll
        for (int c = 0; c < 2; ++c) {
            int bofs = c * 256 + w * 64;
            int idx = bofs + lane;
            gload_lds16(Ae + (size_t)(idx >> 2) * RS + ks * 32 + (idx & 3) * 8,
                        ld + bofs);
        }
    };
    auto load_B = [&](int ks, float (&br)[2][8]) {
        #pragma unroll
        for (int c = 0; c < 2; ++c) {
            int sidx = c * 256 + tid;
            int q = sidx & 3, col = sidx >> 2;
            const float* bp = Be + (size_t)(ks * 32 + q * 8) * N + col;
            #pragma unroll
            for (int jj = 0; jj < 8; ++jj) br[c][jj] = bp[(size_t)jj * N];
        }
    };
    auto write_B = [&](int buf, float (&br)[2][8]) {
        #pragma unroll
        for (int c = 0; c < 2; ++c) {
            int sidx = c * 256 + tid;
            int q = sidx & 3, col = sidx >> 2;
            unsigned int r0, r1, r2_, r3;
            asm("v_cvt_pk_bf16_f32 %0, %1, %2" : "=v"(r0) : "v"(br[c][0]), "v"(br[c][1]));
            asm("v_cvt_pk_bf16_f32 %0, %1, %2" : "=v"(r1) : "v"(br[c][2]), "v"(br[c][3]));
            asm("v_cvt_pk_bf16_f32 %0, %1, %2" : "=v"(r2_) : "v"(br[c][4]), "v"(br[c][5]));
            asm("v_cvt_pk_bf16_f32 %0, %1, %2" : "=v"(r3) : "v"(br[c][6]), "v"(br[c][7]));
            u32x4 r = {r0, r1, r2_, r3};
            lB[buf][col][q] = __builtin_bit_cast(bf16x8, r);   // addr = tid*16: conflict-free
        }
    };

    f32x4 acc[4][4] = {};
    float br[2][8];

    // prologue: A0 via DMA, B0 via regs+cvt
    stage_A(0, 0);
    load_B(0, br);
    write_B(0, br);
    asm volatile("s_waitcnt vmcnt(0) lgkmcnt(0)" ::: "memory");
    __builtin_amdgcn_s_barrier();

    for (int k = 0; k < NK; ++k) {
        const int buf = k & 1;
        if (k + 1 < NK) {
            stage_A(buf ^ 1, k + 1);       // DMA -> other buffer
            load_B(k + 1, br);             // f32 loads issued before MFMA block
        }
        bf16x8 af[4], bfr[4];
        #pragma unroll
        for (int m = 0; m < 4; ++m) af[m] = lA[buf][wm * 64 + m * 16 + lrow][kg];
        #pragma unroll
        for (int n = 0; n < 4; ++n) bfr[n] = lB[buf][wn * 64 + n * 16 + lrow][kg];
        #pragma unroll
        for (int m = 0; m < 4; ++m)
            #pragma unroll
            for (int n = 0; n < 4; ++n)
                acc[m][n] = __builtin_amdgcn_mfma_f32_16x16x32_bf16(
                    af[m], bfr[n], acc[m][n], 0, 0, 0);
        if (k + 1 < NK) write_B(buf ^ 1, br);
        asm volatile("s_waitcnt vmcnt(0) lgkmcnt(0)" ::: "memory");
        __builtin_amdgcn_s_barrier();
    }

    // ---- epilogue ----
    float bv[4];
    #pragma unroll
    for (int n = 0; n < 4; ++n)
        bv[n] = (kb0 == 0) ? bias[e * N + n0 + wn * 64 + n * 16 + lrow] : 0.f;

    if constexpr (YOUT) {
        #pragma unroll
        for (int m = 0; m < 4; ++m) {
            int rbase = m0 + wm * 64 + m * 16 + kg * 4;
            #pragma unroll
            for (int i = 0; i < 4; ++i) {
                #pragma unroll
                for (int n = 0; n < 4; ++n) {
                    int col = n0 + wn * 64 + n * 16 + lrow;
                    atomicAdd((float*)C + ((size_t)e * RP + rbase + i) * N + col,
                              acc[m][n][i] + bv[n]);
                }
            }
        }
    } else {
        #pragma unroll
        for (int n = 0; n < 4; ++n) {
            int col = n0 + wn * 64 + n * 16 + lrow;
            #pragma unroll
            for (int m = 0; m < 4; ++m) {
                int rbase = m0 + wm * 64 + m * 16 + kg * 4;
                #pragma unroll
                for (int i = 0; i < 4; ++i) {
                    float v = acc[m][n][i] + bv[n];
                    if (RELU) v = fmaxf(v, 0.f);
                    ((unsigned short*)C)[((size_t)e * RP + rbase + i) * N + col] = f2bf(v);
                }
            }
        }
    }
}

// ---------------- final scatter: out[t] = kept ? y[slot] : 0 ----------------
__global__ __launch_bounds__(256) void k_scatter(
    const float* __restrict__ y, const int* __restrict__ token_slot,
    float* __restrict__ out)
{
    int t = blockIdx.x;
    int slot = token_slot[t];
    float4* o = reinterpret_cast<float4*>(out + (size_t)t * DM);
    if (slot >= 0) {
        o[threadIdx.x] = reinterpret_cast<const float4*>(
            y + (size_t)slot * DM)[threadIdx.x];
    } else {
        o[threadIdx.x] = make_float4(0.f, 0.f, 0.f, 0.f);
    }
}

extern "C" void kernel_launch(void* const* d_in, const int* in_sizes, int n_in,
                              void* d_out, int out_size, void* d_ws, size_t ws_size,
                              hipStream_t stream)
{
    const float* x  = (const float*)d_in[0];
    const float* rw = (const float*)d_in[1];
    const float* rb = (const float*)d_in[2];
    const float* w1 = (const float*)d_in[3];
    const float* b1 = (const float*)d_in[4];
    const float* w2 = (const float*)d_in[5];
    const float* b2 = (const float*)d_in[6];
    float* out = (float*)d_out;

    char* ws = (char*)d_ws;
    int*   eidx       = (int*)(ws);                      // 16384 int
    int*   s2t        = (int*)(ws + 65536);              // 2560 int
    int*   token_slot = (int*)(ws + 77824);              // 16384 int
    float* sumprob    = (float*)(ws + 143424);           // 8 f32
    float* part = (float*)(ws + 147456);                 // [8][16384][8] f32, 4 MB
    float* y    = (float*)(ws + 147456 + 4194304);       // [NE][RP][DM] f32, 12.6 MB
    unsigned short* xb = (unsigned short*)(ws + 147456 + 4194304 + 12582912);  // 6.29 MB
    unsigned short* h  = (unsigned short*)(ws + 147456 + 4194304 + 12582912 + 6291456); // 25.2 MB

    float* out_lb = out + (size_t)T_TOK * DM;

    hipLaunchKernelGGL(k_logits, dim3(T_TOK / 256, RSPLIT), dim3(256), 0, stream,
                       x, rw, part, sumprob, out_lb);
    hipLaunchKernelGGL(k_reduce, dim3(T_TOK / 256), dim3(256), 0, stream,
                       part, rb, eidx, sumprob);
    hipLaunchKernelGGL(k_scan, dim3(NE), dim3(1024), 0, stream,
                       eidx, s2t, token_slot, sumprob, out_lb);
    hipLaunchKernelGGL(k_gather, dim3(NE * RP), dim3(256), 0, stream,
                       x, s2t, xb, (float4*)y);

    // GEMM1: h = relu(xb @ w1 + b1), w1 f32 consumed directly (inline cvt)
    hipLaunchKernelGGL((k_gemm<32, DM, DFF, 32, true, false, unsigned short>),
                       dim3(8 * 32 * 3), dim3(256), 0, stream, xb, w1, b1, h);

    // GEMM2: y += h @ w2 + b2 (split-K=2 atomics into L2-resident y), w2 f32 direct
    hipLaunchKernelGGL((k_gemm<64, DFF, DM, 8, false, true, float>),
                       dim3(8 * 8 * 3 * 2), dim3(256), 0, stream, h, w2, b2, y);

    hipLaunchKernelGGL(k_scatter, dim3(T_TOK), dim3(256), 0, stream,
                       y, token_slot, out);
}

// Round 12
// 262.879 us; speedup vs baseline: 1.1421x; 1.1421x over previous
//
#include <hip/hip_runtime.h>

#define T_TOK 16384
#define DM 1024
#define DFF 4096
#define NE 8
#define CAP 320
#define RP 384     // per-expert padded rows (3 x 128 tiles)
#define RSPLIT 8
#define KSP (DM / RSPLIT)   // 128

typedef __attribute__((ext_vector_type(8))) short bf16x8;
typedef __attribute__((ext_vector_type(4))) float f32x4;

__device__ __forceinline__ unsigned short f2bf(float f) {
    unsigned int u = __builtin_bit_cast(unsigned int, f);
    u += 0x7FFFu + ((u >> 16) & 1u);   // RNE (finite inputs)
    return (unsigned short)(u >> 16);
}

__device__ __forceinline__ void gload_lds16(const void* g, void* l) {
    __builtin_amdgcn_global_load_lds(
        (const __attribute__((address_space(1))) unsigned int*)g,
        (__attribute__((address_space(3))) unsigned int*)l,
        16, 0, 0);
}

// ---------------- router pass 1 (+ init sumprob/lb in block (0,0)) ----------------
__global__ __launch_bounds__(256) void k_logits(
    const float* __restrict__ x, const float* __restrict__ rw,
    float* __restrict__ part, float* __restrict__ sumprob,
    float* __restrict__ out_lb)
{
    if (blockIdx.x == 0 && blockIdx.y == 0) {
        if (threadIdx.x < NE) sumprob[threadIdx.x] = 0.f;
        if (threadIdx.x == NE) *out_lb = 0.f;
    }
    __shared__ float ws_[KSP][NE];
    __shared__ float xs[256][17];
    const int s = blockIdx.y, t0 = blockIdx.x * 256, tid = threadIdx.x;

    ((float4*)&ws_[0][0])[tid] = ((const float4*)(rw + s * KSP * NE))[tid];

    float a[NE] = {};
    for (int c = 0; c < KSP / 16; ++c) {
        __syncthreads();
        #pragma unroll
        for (int j = 0; j < 4; ++j) {
            int idx = tid + j * 256;
            int row = idx >> 2, f = idx & 3;
            float4 v = *(const float4*)(x + (size_t)(t0 + row) * DM + s * KSP + c * 16 + f * 4);
            xs[row][f * 4 + 0] = v.x; xs[row][f * 4 + 1] = v.y;
            xs[row][f * 4 + 2] = v.z; xs[row][f * 4 + 3] = v.w;
        }
        __syncthreads();
        #pragma unroll
        for (int k = 0; k < 16; ++k) {
            float xv = xs[tid][k];
            const float* wr = &ws_[c * 16 + k][0];
            #pragma unroll
            for (int e = 0; e < NE; ++e) a[e] += xv * wr[e];
        }
    }
    float4* dst = (float4*)(part + ((size_t)s * T_TOK + t0 + tid) * NE);
    dst[0] = make_float4(a[0], a[1], a[2], a[3]);
    dst[1] = make_float4(a[4], a[5], a[6], a[7]);
}

// ---------------- router pass 2 ----------------
__global__ __launch_bounds__(256) void k_reduce(
    const float* __restrict__ part, const float* __restrict__ rb,
    int* __restrict__ eidx, float* __restrict__ sumprob)
{
    int t = blockIdx.x * 256 + threadIdx.x;
    float a[NE];
    #pragma unroll
    for (int e = 0; e < NE; ++e) a[e] = rb[e];
    for (int s = 0; s < RSPLIT; ++s) {        // fixed order -> deterministic
        const float4* p = (const float4*)(part + ((size_t)s * T_TOK + t) * NE);
        float4 v0 = p[0], v1 = p[1];
        a[0] += v0.x; a[1] += v0.y; a[2] += v0.z; a[3] += v0.w;
        a[4] += v1.x; a[5] += v1.y; a[6] += v1.z; a[7] += v1.w;
    }
    float m = a[0]; int bi = 0;
    #pragma unroll
    for (int e = 1; e < NE; ++e) if (a[e] > m) { m = a[e]; bi = e; }
    float p[NE], s = 0.f;
    #pragma unroll
    for (int e = 0; e < NE; ++e) { p[e] = __expf(a[e] - m); s += p[e]; }
    float inv = 1.f / s;
    eidx[t] = bi;
    #pragma unroll
    for (int e = 0; e < NE; ++e) {
        float v = p[e] * inv;
        #pragma unroll
        for (int o = 32; o > 0; o >>= 1) v += __shfl_down(v, o);
        if ((threadIdx.x & 63) == 0) atomicAdd(&sumprob[e], v);
    }
}

// ---------------- per-expert rank scan (+ fused lb-loss term) ----------------
__global__ __launch_bounds__(1024) void k_scan(
    const int* __restrict__ eidx, int* __restrict__ s2t,
    int* __restrict__ token_slot, const float* __restrict__ sumprob,
    float* __restrict__ out_lb)
{
    const int e = blockIdx.x;
    const int tid = threadIdx.x, lane = tid & 63, w = tid >> 6;
    __shared__ int wts[16];

    for (int i = tid; i < CAP; i += 1024) s2t[e * CAP + i] = -1;
    __syncthreads();

    int running = 0;
    for (int base = 0; base < T_TOK; base += 1024) {
        int t = base + tid;
        bool flag = (eidx[t] == e);
        unsigned long long mask = __ballot(flag);
        int wp = __popcll(mask & ((1ull << lane) - 1ull));
        if (lane == 0) wts[w] = __popcll(mask);
        __syncthreads();
        int woff = 0, btot = 0;
        #pragma unroll
        for (int j = 0; j < 16; ++j) { int v = wts[j]; btot += v; if (j < w) woff += v; }
        if (flag) {
            int rank = running + woff + wp;
            if (rank < CAP) {
                s2t[e * CAP + rank] = t;
                token_slot[t] = e * RP + rank;
            } else {
                token_slot[t] = -1;
            }
        }
        running += btot;
        __syncthreads();
    }
    if (tid == 0)
        atomicAdd(out_lb, (float)NE * (float)running * sumprob[e] /
                          ((float)T_TOK * (float)T_TOK));
}

// ---------------- gather kept tokens -> bf16 (+ zero y row) ----------------
__global__ __launch_bounds__(256) void k_gather(
    const float* __restrict__ x, const int* __restrict__ s2t,
    unsigned short* __restrict__ xb, float4* __restrict__ y)
{
    int r = blockIdx.x;
    int e = r / RP, i = r - e * RP;
    int tok = (i < CAP) ? s2t[e * CAP + i] : -1;
    int tid = threadIdx.x;

    y[(size_t)r * (DM / 4) + tid] = make_float4(0.f, 0.f, 0.f, 0.f);

    unsigned short* dst = xb + (size_t)r * DM + tid * 4;
    if (tok >= 0) {
        float4 v = reinterpret_cast<const float4*>(x + (size_t)tok * DM)[tid];
        short4 b = make_short4((short)f2bf(v.x), (short)f2bf(v.y),
                               (short)f2bf(v.z), (short)f2bf(v.w));
        *reinterpret_cast<short4*>(dst) = b;
    } else {
        *reinterpret_cast<short4*>(dst) = make_short4(0, 0, 0, 0);
    }
}

// ---------------- transpose+cvt: f32 [NE][R][C] -> bf16 [NE][chrows][R] ----------
template<int R, int C>
__global__ __launch_bounds__(256) void k_cvt_t(
    const float* __restrict__ src, unsigned short* __restrict__ dst,
    int cbase, int chrows)
{
    __shared__ float t[64][65];
    const int e = blockIdx.z;
    const int r0 = blockIdx.y * 64;
    const int c0g = cbase + blockIdx.x * 64;
    const int tid = threadIdx.x;

    const float* S = src + ((size_t)e * R + r0) * C + c0g;
    int row = tid >> 2, q = tid & 3;
    #pragma unroll
    for (int i = 0; i < 4; ++i) {
        int f = q + i * 4;
        float4 v = *reinterpret_cast<const float4*>(S + (size_t)row * C + f * 4);
        t[row][f * 4 + 0] = v.x; t[row][f * 4 + 1] = v.y;
        t[row][f * 4 + 2] = v.z; t[row][f * 4 + 3] = v.w;
    }
    __syncthreads();

    int orr = tid >> 3, mb = (tid & 7) * 8;
    #pragma unroll
    for (int p = 0; p < 2; ++p) {
        int oc = orr + p * 32;
        bf16x8 v;
        #pragma unroll
        for (int j = 0; j < 8; ++j) v[j] = (short)f2bf(t[mb + j][oc]);
        *reinterpret_cast<bf16x8*>(
            dst + ((size_t)e * chrows + (c0g - cbase) + oc) * R + r0 + mb) = v;
    }
}

// ---------------- grouped GEMM: 128 x (NF*32) tile, round-7 sync, high TLP -------
// A: bf16 [NE][RP][RS] k-contig; Bt: bf16 [NE][chn][RS] n-major k-contig. Both
// DMA-staged (global_load_lds, width 16) into [row][kg] layouts; fragment
// ds_read_b128 covers a contiguous region per wave -> conflict-free.
// Sync: 2-buf, one vmcnt(0)+lgkmcnt(0)+barrier per K-step (proven r7 = best);
// drain hidden by TLP: 24 KB LDS -> 6 blocks/CU (launch_bounds(256,6)).
// XCD-chunk e=j&7 pins each expert's weight stream to one L2.
// MFMA 16x16x32 bf16: A-frag row=lane&15, k=8*(lane>>4)+j; C/D col=lane&15,
// row=4*(lane>>4)+i.
template<int NK, int RS, int NFULL, int NTL, int NF, bool RELU, bool YOUT, typename OutT>
__global__ __launch_bounds__(256, 6) void k_gemm(
    const unsigned short* __restrict__ A, const unsigned short* __restrict__ Bt,
    const float* __restrict__ bias, OutT* __restrict__ C,
    int chn, int n_add)
{
    constexpr int BN = NF * 32;
    constexpr int CB = (BN * 4) / 256;   // B 16B chunks per thread

    __shared__ bf16x8 lA[2][128][4];     // 16 KB
    __shared__ bf16x8 lB[2][BN][4];      // 8 KB at NF=2

    const int j = blockIdx.x;
    const int e = j & 7;                 // XCD-chunk = expert
    const int s = j >> 3;
    const int split = s / (NTL * 3);
    const int r2 = s % (NTL * 3);
    const int nt = r2 / 3, mt = r2 % 3;

    const int m0 = mt * 128;
    const int n0 = nt * BN;
    const int kb0 = split * (NK * 32);
    const int tid = threadIdx.x, lane = tid & 63;
    const int w = tid >> 6, wm = w >> 1, wn = w & 1;
    const int lrow = lane & 15, kg = lane >> 4;

    const unsigned short* Ae = A + ((size_t)e * RP + m0) * RS + kb0;
    const unsigned short* Be = Bt + ((size_t)e * chn + n0) * RS + kb0;

    auto stage_A = [&](int buf, int ks) {
        bf16x8* ld = &lA[buf][0][0];
        #pragma unroll
        for (int c = 0; c < 2; ++c) {
            int bofs = c * 256 + w * 64;
            int idx = bofs + lane;
            gload_lds16(Ae + (size_t)(idx >> 2) * RS + ks * 32 + (idx & 3) * 8,
                        ld + bofs);
        }
    };
    auto stage_B = [&](int buf, int ks) {
        bf16x8* ld = &lB[buf][0][0];
        #pragma unroll
        for (int c = 0; c < CB; ++c) {
            int bofs = c * 256 + w * 64;
            int idx = bofs + lane;
            gload_lds16(Be + (size_t)(idx >> 2) * RS + ks * 32 + (idx & 3) * 8,
                        ld + bofs);
        }
    };

    f32x4 acc[4][NF] = {};

    stage_A(0, 0);
    stage_B(0, 0);
    asm volatile("s_waitcnt vmcnt(0)" ::: "memory");
    __builtin_amdgcn_s_barrier();

    for (int k = 0; k < NK; ++k) {
        const int buf = k & 1;
        if (k + 1 < NK) {
            stage_A(buf ^ 1, k + 1);
            stage_B(buf ^ 1, k + 1);
        }
        bf16x8 af[4], bfr[NF];
        #pragma unroll
        for (int m = 0; m < 4; ++m) af[m] = lA[buf][wm * 64 + m * 16 + lrow][kg];
        #pragma unroll
        for (int n = 0; n < NF; ++n) bfr[n] = lB[buf][wn * NF * 16 + n * 16 + lrow][kg];
        #pragma unroll
        for (int m = 0; m < 4; ++m)
            #pragma unroll
            for (int n = 0; n < NF; ++n)
                acc[m][n] = __builtin_amdgcn_mfma_f32_16x16x32_bf16(
                    af[m], bfr[n], acc[m][n], 0, 0, 0);
        asm volatile("s_waitcnt vmcnt(0) lgkmcnt(0)" ::: "memory");
        __builtin_amdgcn_s_barrier();
    }

    // ---- epilogue ----
    float bv[NF];
    #pragma unroll
    for (int n = 0; n < NF; ++n)
        bv[n] = (kb0 == 0) ? bias[e * NFULL + n_add + n0 + wn * NF * 16 + n * 16 + lrow] : 0.f;

    if constexpr (YOUT) {
        #pragma unroll
        for (int m = 0; m < 4; ++m) {
            int rbase = m0 + wm * 64 + m * 16 + kg * 4;
            #pragma unroll
            for (int i = 0; i < 4; ++i) {
                #pragma unroll
                for (int n = 0; n < NF; ++n) {
                    int col = n_add + n0 + wn * NF * 16 + n * 16 + lrow;
                    atomicAdd((float*)C + ((size_t)e * RP + rbase + i) * NFULL + col,
                              acc[m][n][i] + bv[n]);
                }
            }
        }
    } else {
        #pragma unroll
        for (int n = 0; n < NF; ++n) {
            int col = n_add + n0 + wn * NF * 16 + n * 16 + lrow;
            #pragma unroll
            for (int m = 0; m < 4; ++m) {
                int rbase = m0 + wm * 64 + m * 16 + kg * 4;
                #pragma unroll
                for (int i = 0; i < 4; ++i) {
                    float v = acc[m][n][i] + bv[n];
                    if (RELU) v = fmaxf(v, 0.f);
                    ((unsigned short*)C)[((size_t)e * RP + rbase + i) * NFULL + col] = f2bf(v);
                }
            }
        }
    }
}

// ---------------- final scatter: out[t] = kept ? y[slot] : 0 ----------------
__global__ __launch_bounds__(256) void k_scatter(
    const float* __restrict__ y, const int* __restrict__ token_slot,
    float* __restrict__ out)
{
    int t = blockIdx.x;
    int slot = token_slot[t];
    float4* o = reinterpret_cast<float4*>(out + (size_t)t * DM);
    if (slot >= 0) {
        o[threadIdx.x] = reinterpret_cast<const float4*>(
            y + (size_t)slot * DM)[threadIdx.x];
    } else {
        o[threadIdx.x] = make_float4(0.f, 0.f, 0.f, 0.f);
    }
}

extern "C" void kernel_launch(void* const* d_in, const int* in_sizes, int n_in,
                              void* d_out, int out_size, void* d_ws, size_t ws_size,
                              hipStream_t stream)
{
    const float* x  = (const float*)d_in[0];
    const float* rw = (const float*)d_in[1];
    const float* rb = (const float*)d_in[2];
    const float* w1 = (const float*)d_in[3];
    const float* b1 = (const float*)d_in[4];
    const float* w2 = (const float*)d_in[5];
    const float* b2 = (const float*)d_in[6];
    float* out = (float*)d_out;

    char* ws = (char*)d_ws;
    int*   eidx       = (int*)(ws);                      // 16384 int
    int*   s2t        = (int*)(ws + 65536);              // 2560 int
    int*   token_slot = (int*)(ws + 77824);              // 16384 int
    float* sumprob    = (float*)(ws + 143424);           // 8 f32
    float* part = (float*)(ws + 147456);                 // [8][16384][8] f32, 4 MB
    float* y    = (float*)(ws + 147456 + 4194304);       // [NE][RP][DM] f32, 12.6 MB
    unsigned short* xb = (unsigned short*)(ws + 147456 + 4194304 + 12582912);  // 6.29 MB
    unsigned short* h  = (unsigned short*)(ws + 147456 + 4194304 + 12582912 + 6291456); // 25.2 MB
    unsigned short* W  = (unsigned short*)(ws + 147456 + 4194304 + 12582912 + 6291456 + 25165824);

    size_t wbase = 147456 + 4194304 + 12582912 + 6291456 + 25165824;
    size_t avail = (ws_size > wbase) ? ws_size - wbase : 0;
    int NCH = 1;
    while (NCH < 8 && ((size_t)NE * DFF * DM * 2) / NCH > avail) NCH <<= 1;

    float* out_lb = out + (size_t)T_TOK * DM;

    hipLaunchKernelGGL(k_logits, dim3(T_TOK / 256, RSPLIT), dim3(256), 0, stream,
                       x, rw, part, sumprob, out_lb);
    hipLaunchKernelGGL(k_reduce, dim3(T_TOK / 256), dim3(256), 0, stream,
                       part, rb, eidx, sumprob);
    hipLaunchKernelGGL(k_scan, dim3(NE), dim3(1024), 0, stream,
                       eidx, s2t, token_slot, sumprob, out_lb);
    hipLaunchKernelGGL(k_gather, dim3(NE * RP), dim3(256), 0, stream,
                       x, s2t, xb, (float4*)y);

    // GEMM1: h = relu(xb @ w1 + b1); w1t chunks: bf16 [NE][chn1][DM]
    int chn1 = DFF / NCH;
    for (int c = 0; c < NCH; ++c) {
        hipLaunchKernelGGL((k_cvt_t<DM, DFF>), dim3(chn1 / 64, DM / 64, NE),
                           dim3(256), 0, stream, w1, W, c * chn1, chn1);
        hipLaunchKernelGGL((k_gemm<32, DM, DFF, 64, 2, true, false, unsigned short>),
                           dim3(8 * (chn1 / 64) * 3), dim3(256), 0, stream,
                           xb, W, b1, h, chn1, c * chn1);
    }

    // GEMM2: y += h @ w2 + b2 (split-K=2 atomics, deterministic 2-addend sum)
    int chn2 = DM / NCH;
    for (int c = 0; c < NCH; ++c) {
        hipLaunchKernelGGL((k_cvt_t<DFF, DM>), dim3(chn2 / 64, DFF / 64, NE),
                           dim3(256), 0, stream, w2, W, c * chn2, chn2);
        hipLaunchKernelGGL((k_gemm<64, DFF, DM, 16, 2, false, true, float>),
                           dim3(8 * (chn2 / 64) * 3 * 2), dim3(256), 0, stream,
                           h, W, b2, y, chn2, c * chn2);
    }

    hipLaunchKernelGGL(k_scatter, dim3(T_TOK), dim3(256), 0, stream,
                       y, token_slot, out);
}

// Round 13
// 256.746 us; speedup vs baseline: 1.1694x; 1.0239x over previous
//
#include <hip/hip_runtime.h>

#define T_TOK 16384
#define DM 1024
#define DFF 4096
#define NE 8
#define CAP 320
#define RP 384     // per-expert padded rows (3 x 128 tiles)
#define RSPLIT 8
#define KSP (DM / RSPLIT)   // 128

typedef __attribute__((ext_vector_type(8))) short bf16x8;
typedef __attribute__((ext_vector_type(4))) float f32x4;

__device__ __forceinline__ unsigned short f2bf(float f) {
    unsigned int u = __builtin_bit_cast(unsigned int, f);
    u += 0x7FFFu + ((u >> 16) & 1u);   // RNE (finite inputs)
    return (unsigned short)(u >> 16);
}

__device__ __forceinline__ void gload_lds16(const void* g, void* l) {
    __builtin_amdgcn_global_load_lds(
        (const __attribute__((address_space(1))) unsigned int*)g,
        (__attribute__((address_space(3))) unsigned int*)l,
        16, 0, 0);
}

// ================= device bodies (shared by fused + standalone kernels) ==========

// ---- transpose+cvt 64x64 tile: src f32 [NE][R][C] -> dst bf16 [NE][C][R] ----
template<int R, int C>
__device__ __forceinline__ void cvt_body(char* smem,
    const float* __restrict__ src, unsigned short* __restrict__ dst,
    int bx, int by, int bz)
{
    float (*t)[65] = (float (*)[65])smem;     // 16.6 KB
    const int e = bz;
    const int r0 = by * 64;
    const int c0 = bx * 64;
    const int tid = threadIdx.x;

    const float* S = src + ((size_t)e * R + r0) * C + c0;
    int row = tid >> 2, q = tid & 3;
    #pragma unroll
    for (int i = 0; i < 4; ++i) {
        int f = q + i * 4;
        float4 v = *reinterpret_cast<const float4*>(S + (size_t)row * C + f * 4);
        t[row][f * 4 + 0] = v.x; t[row][f * 4 + 1] = v.y;
        t[row][f * 4 + 2] = v.z; t[row][f * 4 + 3] = v.w;
    }
    __syncthreads();

    int orr = tid >> 3, mb = (tid & 7) * 8;
    #pragma unroll
    for (int p = 0; p < 2; ++p) {
        int oc = orr + p * 32;
        bf16x8 v;
        #pragma unroll
        for (int j = 0; j < 8; ++j) v[j] = (short)f2bf(t[mb + j][oc]);
        *reinterpret_cast<bf16x8*>(
            dst + ((size_t)e * C + c0 + oc) * R + r0 + mb) = v;
    }
}

// ---- grouped GEMM 128x128 (round-7 proven core): C[e]=act(A[e]@Bt[e]^T+bias) ----
// A: bf16 [NE][RP][RS] k-contig; Bt: bf16 [NE][NFULL][RS] n-major k-contig.
// Both DMA-staged (global_load_lds w16) into [row][kg]; fragment ds_read_b128 is
// a contiguous 1KB/wave -> conflict-free. 2-buf, vmcnt(0)+lgkmcnt(0)+barrier per
// K-step; drain hidden by TLP. XCD-chunk e=j&7 pins expert weights to one L2.
// MFMA 16x16x32 bf16: A-frag row=lane&15, k=8*(lane>>4)+j; C/D col=lane&15,
// row=4*(lane>>4)+i.
template<int NK, int RS, int NFULL, int NTL, bool RELU, bool YOUT, typename OutT>
__device__ __forceinline__ void gemm_body(char* smem, int j,
    const unsigned short* __restrict__ A, const unsigned short* __restrict__ Bt,
    const float* __restrict__ bias, OutT* __restrict__ C)
{
    bf16x8 (*lA)[128][4] = (bf16x8 (*)[128][4])smem;             // [2][128][4]
    bf16x8 (*lB)[128][4] = (bf16x8 (*)[128][4])(smem + 16384);   // [2][128][4]

    const int e = j & 7;
    const int s = j >> 3;
    const int split = s / (NTL * 3);
    const int r2 = s % (NTL * 3);
    const int nt = r2 / 3, mt = r2 % 3;

    const int m0 = mt * 128;
    const int n0 = nt * 128;
    const int kb0 = split * (NK * 32);
    const int tid = threadIdx.x, lane = tid & 63;
    const int w = tid >> 6, wm = w >> 1, wn = w & 1;
    const int lrow = lane & 15, kg = lane >> 4;

    const unsigned short* Ae = A + ((size_t)e * RP + m0) * RS + kb0;
    const unsigned short* Be = Bt + ((size_t)e * NFULL + n0) * RS + kb0;

    auto stage = [&](const unsigned short* gb, bf16x8* ld, int ks) {
        #pragma unroll
        for (int c = 0; c < 2; ++c) {
            int bofs = c * 256 + w * 64;
            int idx = bofs + lane;
            gload_lds16(gb + (size_t)(idx >> 2) * RS + ks * 32 + (idx & 3) * 8,
                        ld + bofs);
        }
    };

    f32x4 acc[4][4] = {};

    stage(Ae, &lA[0][0][0], 0);
    stage(Be, &lB[0][0][0], 0);
    asm volatile("s_waitcnt vmcnt(0)" ::: "memory");
    __builtin_amdgcn_s_barrier();

    for (int ks = 0; ks < NK; ++ks) {
        const int buf = ks & 1;
        if (ks + 1 < NK) {
            stage(Ae, &lA[buf ^ 1][0][0], ks + 1);
            stage(Be, &lB[buf ^ 1][0][0], ks + 1);
        }
        bf16x8 af[4], bfr[4];
        #pragma unroll
        for (int m = 0; m < 4; ++m) af[m] = lA[buf][wm * 64 + m * 16 + lrow][kg];
        #pragma unroll
        for (int n = 0; n < 4; ++n) bfr[n] = lB[buf][wn * 64 + n * 16 + lrow][kg];
        #pragma unroll
        for (int m = 0; m < 4; ++m)
            #pragma unroll
            for (int n = 0; n < 4; ++n)
                acc[m][n] = __builtin_amdgcn_mfma_f32_16x16x32_bf16(
                    af[m], bfr[n], acc[m][n], 0, 0, 0);
        asm volatile("s_waitcnt vmcnt(0) lgkmcnt(0)" ::: "memory");
        __builtin_amdgcn_s_barrier();
    }

    float bv[4];
    #pragma unroll
    for (int n = 0; n < 4; ++n)
        bv[n] = (kb0 == 0) ? bias[e * NFULL + n0 + wn * 64 + n * 16 + lrow] : 0.f;

    if constexpr (YOUT) {
        #pragma unroll
        for (int m = 0; m < 4; ++m) {
            int rbase = m0 + wm * 64 + m * 16 + kg * 4;
            #pragma unroll
            for (int i = 0; i < 4; ++i) {
                #pragma unroll
                for (int n = 0; n < 4; ++n) {
                    int col = n0 + wn * 64 + n * 16 + lrow;
                    atomicAdd((float*)C + ((size_t)e * RP + rbase + i) * NFULL + col,
                              acc[m][n][i] + bv[n]);
                }
            }
        }
    } else {
        #pragma unroll
        for (int n = 0; n < 4; ++n) {
            int col = n0 + wn * 64 + n * 16 + lrow;
            #pragma unroll
            for (int m = 0; m < 4; ++m) {
                int rbase = m0 + wm * 64 + m * 16 + kg * 4;
                #pragma unroll
                for (int i = 0; i < 4; ++i) {
                    float v = acc[m][n][i] + bv[n];
                    if (RELU) v = fmaxf(v, 0.f);
                    ((unsigned short*)C)[((size_t)e * RP + rbase + i) * NFULL + col] = f2bf(v);
                }
            }
        }
    }
}

// ================= kernels =======================================================

// ---- phase 1 (fused): router logits [blocks 0..511] || cvt1 w1->W1 [512..8703] ---
__global__ __launch_bounds__(256) void k_p1(
    const float* __restrict__ x, const float* __restrict__ rw,
    float* __restrict__ part, float* __restrict__ sumprob,
    float* __restrict__ out_lb, const float* __restrict__ w1,
    unsigned short* __restrict__ W1)
{
    extern __shared__ __align__(16) char smem[];
    const int b = blockIdx.x;
    if (b < 512) {
        if (b == 0) {
            if (threadIdx.x < NE) sumprob[threadIdx.x] = 0.f;
            if (threadIdx.x == NE) *out_lb = 0.f;
        }
        float (*ws_)[NE] = (float (*)[NE])smem;               // 4 KB
        float (*xs)[17]  = (float (*)[17])(smem + 4096);      // 17.4 KB
        const int s = b >> 6, t0 = (b & 63) * 256, tid = threadIdx.x;

        ((float4*)&ws_[0][0])[tid] = ((const float4*)(rw + s * KSP * NE))[tid];

        float a[NE] = {};
        for (int c = 0; c < KSP / 16; ++c) {
            __syncthreads();
            #pragma unroll
            for (int jj = 0; jj < 4; ++jj) {
                int idx = tid + jj * 256;
                int row = idx >> 2, f = idx & 3;
                float4 v = *(const float4*)(x + (size_t)(t0 + row) * DM + s * KSP + c * 16 + f * 4);
                xs[row][f * 4 + 0] = v.x; xs[row][f * 4 + 1] = v.y;
                xs[row][f * 4 + 2] = v.z; xs[row][f * 4 + 3] = v.w;
            }
            __syncthreads();
            #pragma unroll
            for (int k = 0; k < 16; ++k) {
                float xv = xs[tid][k];
                const float* wr = &ws_[c * 16 + k][0];
                #pragma unroll
                for (int e = 0; e < NE; ++e) a[e] += xv * wr[e];
            }
        }
        float4* dst = (float4*)(part + ((size_t)s * T_TOK + t0 + tid) * NE);
        dst[0] = make_float4(a[0], a[1], a[2], a[3]);
        dst[1] = make_float4(a[4], a[5], a[6], a[7]);
    } else {
        int c = b - 512;    // cvt1 grid (64, 16, 8)
        cvt_body<DM, DFF>(smem, w1, W1, c & 63, (c >> 6) & 15, c >> 10);
    }
}

// ---- router pass 2 ----
__global__ __launch_bounds__(256) void k_reduce(
    const float* __restrict__ part, const float* __restrict__ rb,
    int* __restrict__ eidx, float* __restrict__ sumprob)
{
    int t = blockIdx.x * 256 + threadIdx.x;
    float a[NE];
    #pragma unroll
    for (int e = 0; e < NE; ++e) a[e] = rb[e];
    for (int s = 0; s < RSPLIT; ++s) {        // fixed order -> deterministic
        const float4* p = (const float4*)(part + ((size_t)s * T_TOK + t) * NE);
        float4 v0 = p[0], v1 = p[1];
        a[0] += v0.x; a[1] += v0.y; a[2] += v0.z; a[3] += v0.w;
        a[4] += v1.x; a[5] += v1.y; a[6] += v1.z; a[7] += v1.w;
    }
    float m = a[0]; int bi = 0;
    #pragma unroll
    for (int e = 1; e < NE; ++e) if (a[e] > m) { m = a[e]; bi = e; }
    float p[NE], s = 0.f;
    #pragma unroll
    for (int e = 0; e < NE; ++e) { p[e] = __expf(a[e] - m); s += p[e]; }
    float inv = 1.f / s;
    eidx[t] = bi;
    #pragma unroll
    for (int e = 0; e < NE; ++e) {
        float v = p[e] * inv;
        #pragma unroll
        for (int o = 32; o > 0; o >>= 1) v += __shfl_down(v, o);
        if ((threadIdx.x & 63) == 0) atomicAdd(&sumprob[e], v);
    }
}

// ---- per-expert rank scan (+ fused lb-loss term) ----
__global__ __launch_bounds__(1024) void k_scan(
    const int* __restrict__ eidx, int* __restrict__ s2t,
    int* __restrict__ token_slot, const float* __restrict__ sumprob,
    float* __restrict__ out_lb)
{
    const int e = blockIdx.x;
    const int tid = threadIdx.x, lane = tid & 63, w = tid >> 6;
    __shared__ int wts[16];

    for (int i = tid; i < CAP; i += 1024) s2t[e * CAP + i] = -1;
    __syncthreads();

    int running = 0;
    for (int base = 0; base < T_TOK; base += 1024) {
        int t = base + tid;
        bool flag = (eidx[t] == e);
        unsigned long long mask = __ballot(flag);
        int wp = __popcll(mask & ((1ull << lane) - 1ull));
        if (lane == 0) wts[w] = __popcll(mask);
        __syncthreads();
        int woff = 0, btot = 0;
        #pragma unroll
        for (int j = 0; j < 16; ++j) { int v = wts[j]; btot += v; if (j < w) woff += v; }
        if (flag) {
            int rank = running + woff + wp;
            if (rank < CAP) {
                s2t[e * CAP + rank] = t;
                token_slot[t] = e * RP + rank;
            } else {
                token_slot[t] = -1;
            }
        }
        running += btot;
        __syncthreads();
    }
    if (tid == 0)
        atomicAdd(out_lb, (float)NE * (float)running * sumprob[e] /
                          ((float)T_TOK * (float)T_TOK));
}

// ---- gather kept tokens -> bf16 (+ zero y row) ----
__global__ __launch_bounds__(256) void k_gather(
    const float* __restrict__ x, const int* __restrict__ s2t,
    unsigned short* __restrict__ xb, float4* __restrict__ y)
{
    int r = blockIdx.x;
    int e = r / RP, i = r - e * RP;
    int tok = (i < CAP) ? s2t[e * CAP + i] : -1;
    int tid = threadIdx.x;

    y[(size_t)r * (DM / 4) + tid] = make_float4(0.f, 0.f, 0.f, 0.f);

    unsigned short* dst = xb + (size_t)r * DM + tid * 4;
    if (tok >= 0) {
        float4 v = reinterpret_cast<const float4*>(x + (size_t)tok * DM)[tid];
        short4 b = make_short4((short)f2bf(v.x), (short)f2bf(v.y),
                               (short)f2bf(v.z), (short)f2bf(v.w));
        *reinterpret_cast<short4*>(dst) = b;
    } else {
        *reinterpret_cast<short4*>(dst) = make_short4(0, 0, 0, 0);
    }
}

// ---- phase 2 (fused): gemm1 [blocks 0..767] || cvt2 w2->W2 [768..8959] ----
__global__ __launch_bounds__(256) void k_p2(
    const unsigned short* __restrict__ xb, const unsigned short* __restrict__ W1,
    const float* __restrict__ b1, unsigned short* __restrict__ h,
    const float* __restrict__ w2, unsigned short* __restrict__ W2)
{
    extern __shared__ __align__(16) char smem[];
    const int b = blockIdx.x;
    if (b < 768) {
        gemm_body<32, DM, DFF, 32, true, false, unsigned short>(smem, b, xb, W1, b1, h);
    } else {
        int c = b - 768;    // cvt2 grid (16, 64, 8)
        cvt_body<DFF, DM>(smem, w2, W2, c & 15, (c >> 4) & 63, c >> 10);
    }
}

// ---- gemm2 standalone: y += h @ w2t + b2, split-K=2 (2-addend deterministic) ----
__global__ __launch_bounds__(256, 4) void k_gemm2(
    const unsigned short* __restrict__ h, const unsigned short* __restrict__ W2,
    const float* __restrict__ b2, float* __restrict__ y)
{
    __shared__ __align__(16) char smem[32768];
    gemm_body<64, DFF, DM, 8, false, true, float>(smem, blockIdx.x, h, W2, b2, y);
}

// ---- final scatter: out[t] = kept ? y[slot] : 0 ----
__global__ __launch_bounds__(256) void k_scatter(
    const float* __restrict__ y, const int* __restrict__ token_slot,
    float* __restrict__ out)
{
    int t = blockIdx.x;
    int slot = token_slot[t];
    float4* o = reinterpret_cast<float4*>(out + (size_t)t * DM);
    if (slot >= 0) {
        o[threadIdx.x] = reinterpret_cast<const float4*>(
            y + (size_t)slot * DM)[threadIdx.x];
    } else {
        o[threadIdx.x] = make_float4(0.f, 0.f, 0.f, 0.f);
    }
}

extern "C" void kernel_launch(void* const* d_in, const int* in_sizes, int n_in,
                              void* d_out, int out_size, void* d_ws, size_t ws_size,
                              hipStream_t stream)
{
    const float* x  = (const float*)d_in[0];
    const float* rw = (const float*)d_in[1];
    const float* rb = (const float*)d_in[2];
    const float* w1 = (const float*)d_in[3];
    const float* b1 = (const float*)d_in[4];
    const float* w2 = (const float*)d_in[5];
    const float* b2 = (const float*)d_in[6];
    float* out = (float*)d_out;

    char* ws = (char*)d_ws;
    int*   eidx       = (int*)(ws);                          // 64 KB
    int*   s2t        = (int*)(ws + 65536);                  // 10 KB
    int*   token_slot = (int*)(ws + 77824);                  // 64 KB
    float* sumprob    = (float*)(ws + 143424);               // 8 f32
    float* part = (float*)(ws + 147456);                     // 4 MB
    float* y    = (float*)(ws + 4341760);                    // 12.6 MB
    unsigned short* xb = (unsigned short*)(ws + 16924672);   // 6.29 MB
    unsigned short* h  = (unsigned short*)(ws + 23216128);   // 25.2 MB
    unsigned short* W1 = (unsigned short*)(ws + 48381952);   // 67 MB
    unsigned short* W2 = (unsigned short*)(ws + 115490816);  // 67 MB (ends ~183 MB)

    float* out_lb = out + (size_t)T_TOK * DM;

    // L1: router logits || w1 transpose-cvt
    hipLaunchKernelGGL(k_p1, dim3(512 + 8192), dim3(256), 21504, stream,
                       x, rw, part, sumprob, out_lb, w1, W1);
    // L2: reduce/softmax/argmax
    hipLaunchKernelGGL(k_reduce, dim3(T_TOK / 256), dim3(256), 0, stream,
                       part, rb, eidx, sumprob);
    // L3: per-expert rank scan + lb loss
    hipLaunchKernelGGL(k_scan, dim3(NE), dim3(1024), 0, stream,
                       eidx, s2t, token_slot, sumprob, out_lb);
    // L4: gather + zero y
    hipLaunchKernelGGL(k_gather, dim3(NE * RP), dim3(256), 0, stream,
                       x, s2t, xb, (float4*)y);
    // L5: gemm1 (h = relu(xb@W1^T + b1)) || w2 transpose-cvt
    hipLaunchKernelGGL(k_p2, dim3(768 + 8192), dim3(256), 32768, stream,
                       xb, W1, b1, h, w2, W2);
    // L6: gemm2 (y += h@W2^T + b2, split-K=2)
    hipLaunchKernelGGL(k_gemm2, dim3(8 * 8 * 3 * 2), dim3(256), 0, stream,
                       h, W2, b2, y);
    // L7: scatter to out
    hipLaunchKernelGGL(k_scatter, dim3(T_TOK), dim3(256), 0, stream,
                       y, token_slot, out);
}